// Round 1
// baseline (432.838 us; speedup 1.0000x reference)
//
#include <hip/hip_runtime.h>
#include <stdint.h>

#define GAS __attribute__((address_space(1)))
#define LAS __attribute__((address_space(3)))

typedef __attribute__((ext_vector_type(8))) short short8;
typedef __attribute__((ext_vector_type(4))) float f32x4;

static constexpr int N_TOK = 2048;
static constexpr int DM    = 1024;
static constexpr int DF    = 4096;
static constexpr int KP    = 4;

// ---------- helpers ----------
__device__ inline unsigned short f2bf(float f) {
  union { float f; uint32_t u; } v; v.f = f;
  uint32_t u = v.u;
  u += 0x7FFFu + ((u >> 16) & 1u);   // RNE
  return (unsigned short)(u >> 16);
}

// jax.nn.gelu default: tanh approximation. Overflow-safe tanh via exp.
__device__ inline float gelu_tanh(float x) {
  float z = 0.7978845608028654f * (x + 0.044715f * x * x * x);
  float t = 1.0f - 2.0f / (1.0f + __expf(2.0f * z));
  return 0.5f * x * (1.0f + t);
}

__device__ inline void gload_lds16(const void* g, void* l) {
  __builtin_amdgcn_global_load_lds((const GAS void*)g, (LAS void*)l, 16, 0, 0);
}

// ---------- kernel 1: gates (softmax routing) + bf16 cast of tokens ----------
// one wave per token; 512 blocks x 256 threads
__global__ __launch_bounds__(256) void prep_kernel(
    const float* __restrict__ tokens, const float* __restrict__ pb,
    float* __restrict__ gates, unsigned short* __restrict__ xb) {
  const int wave = threadIdx.x >> 6, lane = threadIdx.x & 63;
  const int n = blockIdx.x * 4 + wave;
  float s0 = 0.f, s1 = 0.f, s2 = 0.f, s3 = 0.f;
  const float4* tr = (const float4*)(tokens + (size_t)n * DM);
#pragma unroll
  for (int j = 0; j < 4; ++j) {
    int idx = j * 64 + lane;          // float4 index in row (256 per row)
    float4 t = tr[idx];
    ushort4 b;
    b.x = f2bf(t.x); b.y = f2bf(t.y); b.z = f2bf(t.z); b.w = f2bf(t.w);
    *(ushort4*)(xb + (size_t)n * DM + idx * 4) = b;
    float4 q;
    q = ((const float4*)(pb + 0 * DM))[idx]; s0 += t.x*q.x + t.y*q.y + t.z*q.z + t.w*q.w;
    q = ((const float4*)(pb + 1 * DM))[idx]; s1 += t.x*q.x + t.y*q.y + t.z*q.z + t.w*q.w;
    q = ((const float4*)(pb + 2 * DM))[idx]; s2 += t.x*q.x + t.y*q.y + t.z*q.z + t.w*q.w;
    q = ((const float4*)(pb + 3 * DM))[idx]; s3 += t.x*q.x + t.y*q.y + t.z*q.z + t.w*q.w;
  }
#pragma unroll
  for (int off = 32; off > 0; off >>= 1) {
    s0 += __shfl_xor(s0, off);
    s1 += __shfl_xor(s1, off);
    s2 += __shfl_xor(s2, off);
    s3 += __shfl_xor(s3, off);
  }
  if (lane == 0) {
    float m = fmaxf(fmaxf(s0, s1), fmaxf(s2, s3));
    float e0 = __expf(s0 - m), e1 = __expf(s1 - m), e2 = __expf(s2 - m), e3 = __expf(s3 - m);
    float inv = 1.0f / (e0 + e1 + e2 + e3);
    float4 g; g.x = e0 * inv; g.y = e1 * inv; g.z = e2 * inv; g.w = e3 * inv;
    *(float4*)(gates + n * 4) = g;
  }
}

// ---------- kernel 2: build W1eff^T bf16: w1t[k][f][d] = sum_r c1[k,a,x,r]*c2[k,r,b,y]
// d = a*32+b, f = x*64+y.  grid = K*DF blocks (one (k,f) row each), 256 threads.
__global__ __launch_bounds__(256) void build_w1(
    const float* __restrict__ c1, const float* __restrict__ c2,
    unsigned short* __restrict__ w1t) {
  const int kf = blockIdx.x;
  const int k = kf >> 12, f = kf & 4095;
  const int x = f >> 6, y = f & 63;
  __shared__ float s1[32 * 16];  // [a][r]
  __shared__ float s2[16 * 32];  // [r][b]
  const int t = threadIdx.x;
  for (int i = t; i < 512; i += 256) {
    int a = i >> 4, r = i & 15;
    s1[i] = c1[(((size_t)(k * 32 + a)) * 64 + x) * 16 + r];
  }
  for (int i = t; i < 512; i += 256) {
    int r = i >> 5, b = i & 31;
    s2[i] = c2[(((size_t)(k * 16 + r)) * 32 + b) * 64 + y];
  }
  __syncthreads();
  unsigned short* wrow = w1t + ((size_t)k * DF + f) * DM;
#pragma unroll
  for (int j = 0; j < 4; ++j) {
    int d = t + j * 256;
    int a = d >> 5, b = d & 31;
    float s = 0.f;
#pragma unroll
    for (int r = 0; r < 16; ++r) s += s1[a * 16 + r] * s2[r * 32 + b];
    wrow[d] = f2bf(s);
  }
}

// ---------- kernel 3: build W2eff^T bf16: w2t[k][d][f] = sum_r c1[k,a,x,r]*c2[k,r,b,y]
// f = a*64+b, d = x*32+y.  grid = K*DM blocks, 256 threads.
__global__ __launch_bounds__(256) void build_w2(
    const float* __restrict__ c1, const float* __restrict__ c2,
    unsigned short* __restrict__ w2t) {
  const int kd = blockIdx.x;
  const int k = kd >> 10, d = kd & 1023;
  const int x = d >> 5, y = d & 31;
  __shared__ float s1[64 * 16];  // [a][r]
  __shared__ float s2[16 * 64];  // [r][b]
  const int t = threadIdx.x;
  for (int i = t; i < 1024; i += 256) {
    int a = i >> 4, r = i & 15;
    s1[i] = c1[(((size_t)(k * 64 + a)) * 32 + x) * 16 + r];
  }
  for (int i = t; i < 1024; i += 256) {
    int r = i >> 6, b = i & 63;
    s2[i] = c2[(((size_t)(k * 16 + r)) * 64 + b) * 32 + y];
  }
  __syncthreads();
  unsigned short* wrow = w2t + ((size_t)k * DM + d) * DF;
#pragma unroll
  for (int j = 0; j < 16; ++j) {
    int f = t + j * 256;
    int a = f >> 6, b = f & 63;
    float s = 0.f;
#pragma unroll
    for (int r = 0; r < 16; ++r) s += s1[a * 16 + r] * s2[r * 64 + b];
    wrow[f] = f2bf(s);
  }
}

// ---------- kernel 4: GEMM1  hg[k][n][f] = bf16( gelu(x @ W1[k])[n,f] * gates[n,k] )
// A = xb [2048][1024] bf16 rm; Bt = w1t[k] [4096][1024] bf16 rm (k-dim contiguous).
// 128x128 tile, BK=64, 256 thr (4 waves, each 64x64 = 4x4 mfma 16x16x32).
__global__ __launch_bounds__(256) void gemm1(
    const unsigned short* __restrict__ xb, const unsigned short* __restrict__ w1t,
    const float* __restrict__ gates, unsigned short* __restrict__ hg) {
  __shared__ __align__(16) unsigned short As[128 * 64];
  __shared__ __align__(16) unsigned short Bs[128 * 64];
  const int t = threadIdx.x, lane = t & 63, wv = t >> 6;
  const int m0 = blockIdx.x * 128, n0 = blockIdx.y * 128, kp = blockIdx.z;
  const unsigned short* B = w1t + (size_t)kp * DF * DM;
  f32x4 acc[4][4] = {};
  const int srow = t >> 3, schunk = (t & 7) * 8;
  const int wrow = (wv >> 1) * 64, wcol = (wv & 1) * 64;
  const int fr = lane & 15, fq8 = (lane >> 4) * 8;
  char* AsB = (char*)As;
  char* BsB = (char*)Bs;
  for (int k0 = 0; k0 < DM; k0 += 64) {
#pragma unroll
    for (int i = 0; i < 4; ++i) {
      int row = i * 32 + srow;
      gload_lds16(xb + (size_t)(m0 + row) * DM + k0 + schunk, AsB + i * 4096 + t * 16);
      gload_lds16(B + (size_t)(n0 + row) * DM + k0 + schunk, BsB + i * 4096 + t * 16);
    }
    __syncthreads();
#pragma unroll
    for (int kk = 0; kk < 2; ++kk) {
      short8 a[4], b[4];
#pragma unroll
      for (int mi = 0; mi < 4; ++mi)
        a[mi] = *(const short8*)(As + (wrow + mi * 16 + fr) * 64 + kk * 32 + fq8);
#pragma unroll
      for (int ni = 0; ni < 4; ++ni)
        b[ni] = *(const short8*)(Bs + (wcol + ni * 16 + fr) * 64 + kk * 32 + fq8);
#pragma unroll
      for (int mi = 0; mi < 4; ++mi)
#pragma unroll
        for (int ni = 0; ni < 4; ++ni)
          acc[mi][ni] = __builtin_amdgcn_mfma_f32_16x16x32_bf16(a[mi], b[ni], acc[mi][ni], 0, 0, 0);
    }
    __syncthreads();
  }
  // epilogue: gelu * gate, store bf16
  unsigned short* H = hg + (size_t)kp * N_TOK * DF;
  const int rq = (lane >> 4) * 4;
#pragma unroll
  for (int mi = 0; mi < 4; ++mi) {
#pragma unroll
    for (int i = 0; i < 4; ++i) {
      int row = m0 + wrow + mi * 16 + rq + i;
      float g = gates[row * 4 + kp];
#pragma unroll
      for (int ni = 0; ni < 4; ++ni) {
        float v = acc[mi][ni][i];
        H[(size_t)row * DF + n0 + wcol + ni * 16 + fr] = f2bf(gelu_tanh(v) * g);
      }
    }
  }
}

// ---------- kernel 5: GEMM2  out[n][d] = sum_k (1+pw[k][d]) * (hg[k] @ W2[k])[n,d]
// A = hg[k] [2048][4096]; Bt = w2t[k] [1024][4096]. 64x64 tile, BK=64, k-loop inside.
__global__ __launch_bounds__(256) void gemm2(
    const unsigned short* __restrict__ hg, const unsigned short* __restrict__ w2t,
    const float* __restrict__ pw, float* __restrict__ out) {
  __shared__ __align__(16) unsigned short As[64 * 64];
  __shared__ __align__(16) unsigned short Bs[64 * 64];
  const int t = threadIdx.x, lane = t & 63, wv = t >> 6;
  const int m0 = blockIdx.x * 64, n0 = blockIdx.y * 64;
  const int wrow = (wv >> 1) * 32, wcol = (wv & 1) * 32;
  const int fr = lane & 15, fq8 = (lane >> 4) * 8;
  const int srow = t >> 3, schunk = (t & 7) * 8;
  f32x4 tot[2][2] = {};
  char* AsB = (char*)As;
  char* BsB = (char*)Bs;
  for (int kp = 0; kp < KP; ++kp) {
    f32x4 pacc[2][2] = {};
    const unsigned short* A = hg + (size_t)kp * N_TOK * DF;
    const unsigned short* B = w2t + (size_t)kp * DM * DF;
    for (int k0 = 0; k0 < DF; k0 += 64) {
#pragma unroll
      for (int i = 0; i < 2; ++i) {
        int row = i * 32 + srow;
        gload_lds16(A + (size_t)(m0 + row) * DF + k0 + schunk, AsB + i * 4096 + t * 16);
        gload_lds16(B + (size_t)(n0 + row) * DF + k0 + schunk, BsB + i * 4096 + t * 16);
      }
      __syncthreads();
#pragma unroll
      for (int kk = 0; kk < 2; ++kk) {
        short8 a[2], b[2];
#pragma unroll
        for (int mi = 0; mi < 2; ++mi)
          a[mi] = *(const short8*)(As + (wrow + mi * 16 + fr) * 64 + kk * 32 + fq8);
#pragma unroll
        for (int ni = 0; ni < 2; ++ni)
          b[ni] = *(const short8*)(Bs + (wcol + ni * 16 + fr) * 64 + kk * 32 + fq8);
#pragma unroll
        for (int mi = 0; mi < 2; ++mi)
#pragma unroll
          for (int ni = 0; ni < 2; ++ni)
            pacc[mi][ni] = __builtin_amdgcn_mfma_f32_16x16x32_bf16(a[mi], b[ni], pacc[mi][ni], 0, 0, 0);
      }
      __syncthreads();
    }
    float pwv0 = 1.0f + pw[kp * DM + n0 + wcol + fr];
    float pwv1 = 1.0f + pw[kp * DM + n0 + wcol + 16 + fr];
#pragma unroll
    for (int mi = 0; mi < 2; ++mi) {
      tot[mi][0] += pwv0 * pacc[mi][0];
      tot[mi][1] += pwv1 * pacc[mi][1];
    }
  }
  const int rq = (lane >> 4) * 4;
#pragma unroll
  for (int mi = 0; mi < 2; ++mi)
#pragma unroll
    for (int i = 0; i < 4; ++i) {
      int row = m0 + wrow + mi * 16 + rq + i;
#pragma unroll
      for (int ni = 0; ni < 2; ++ni)
        out[(size_t)row * DM + n0 + wcol + ni * 16 + fr] = tot[mi][ni][i];
    }
}

// ---------- launcher ----------
extern "C" void kernel_launch(void* const* d_in, const int* in_sizes, int n_in,
                              void* d_out, int out_size, void* d_ws, size_t ws_size,
                              hipStream_t stream) {
  const float* tokens = (const float*)d_in[0];
  const float* f1c1   = (const float*)d_in[1];
  const float* f1c2   = (const float*)d_in[2];
  const float* f2c1   = (const float*)d_in[3];
  const float* f2c2   = (const float*)d_in[4];
  const float* pb     = (const float*)d_in[5];
  const float* pw     = (const float*)d_in[6];
  float* out = (float*)d_out;

  char* ws = (char*)d_ws;
  unsigned short* xb  = (unsigned short*)(ws);                       //   4 MB
  unsigned short* w1t = (unsigned short*)(ws + (4ull  << 20));       //  32 MB
  unsigned short* w2t = (unsigned short*)(ws + (36ull << 20));       //  32 MB
  unsigned short* hg  = (unsigned short*)(ws + (68ull << 20));       //  64 MB
  float*          gates = (float*)(ws + (132ull << 20));             //  32 KB

  hipLaunchKernelGGL(prep_kernel, dim3(512), dim3(256), 0, stream, tokens, pb, gates, xb);
  hipLaunchKernelGGL(build_w1, dim3(KP * DF), dim3(256), 0, stream, f1c1, f1c2, w1t);
  hipLaunchKernelGGL(build_w2, dim3(KP * DM), dim3(256), 0, stream, f2c1, f2c2, w2t);
  hipLaunchKernelGGL(gemm1, dim3(16, 32, KP), dim3(256), 0, stream, xb, w1t, gates, hg);
  hipLaunchKernelGGL(gemm2, dim3(32, 16), dim3(256), 0, stream, hg, w2t, pw, out);
}

// Round 2
// 323.072 us; speedup vs baseline: 1.3398x; 1.3398x over previous
//
#include <hip/hip_runtime.h>
#include <stdint.h>

#define GAS __attribute__((address_space(1)))
#define LAS __attribute__((address_space(3)))

typedef __attribute__((ext_vector_type(8))) short short8;
typedef __attribute__((ext_vector_type(4))) float f32x4;

static constexpr int N_TOK = 2048;
static constexpr int DM    = 1024;
static constexpr int DF    = 4096;
static constexpr int KP    = 4;

// ---------- helpers ----------
__device__ inline unsigned short f2bf(float f) {
  union { float f; uint32_t u; } v; v.f = f;
  uint32_t u = v.u;
  u += 0x7FFFu + ((u >> 16) & 1u);   // RNE
  return (unsigned short)(u >> 16);
}

// jax.nn.gelu default: tanh approximation. Overflow-safe tanh via exp.
__device__ inline float gelu_tanh(float x) {
  float z = 0.7978845608028654f * (x + 0.044715f * x * x * x);
  float t = 1.0f - 2.0f / (1.0f + __expf(2.0f * z));
  return 0.5f * x * (1.0f + t);
}

__device__ inline void gload_lds16(const void* g, void* l) {
  __builtin_amdgcn_global_load_lds((const GAS void*)g, (LAS void*)l, 16, 0, 0);
}

// ---------- kernel 1: gates (softmax routing) + bf16 cast of tokens ----------
__global__ __launch_bounds__(256) void prep_kernel(
    const float* __restrict__ tokens, const float* __restrict__ pb,
    float* __restrict__ gates, unsigned short* __restrict__ xb) {
  const int wave = threadIdx.x >> 6, lane = threadIdx.x & 63;
  const int n = blockIdx.x * 4 + wave;
  float s0 = 0.f, s1 = 0.f, s2 = 0.f, s3 = 0.f;
  const float4* tr = (const float4*)(tokens + (size_t)n * DM);
#pragma unroll
  for (int j = 0; j < 4; ++j) {
    int idx = j * 64 + lane;
    float4 t = tr[idx];
    ushort4 b;
    b.x = f2bf(t.x); b.y = f2bf(t.y); b.z = f2bf(t.z); b.w = f2bf(t.w);
    *(ushort4*)(xb + (size_t)n * DM + idx * 4) = b;
    float4 q;
    q = ((const float4*)(pb + 0 * DM))[idx]; s0 += t.x*q.x + t.y*q.y + t.z*q.z + t.w*q.w;
    q = ((const float4*)(pb + 1 * DM))[idx]; s1 += t.x*q.x + t.y*q.y + t.z*q.z + t.w*q.w;
    q = ((const float4*)(pb + 2 * DM))[idx]; s2 += t.x*q.x + t.y*q.y + t.z*q.z + t.w*q.w;
    q = ((const float4*)(pb + 3 * DM))[idx]; s3 += t.x*q.x + t.y*q.y + t.z*q.z + t.w*q.w;
  }
#pragma unroll
  for (int off = 32; off > 0; off >>= 1) {
    s0 += __shfl_xor(s0, off);
    s1 += __shfl_xor(s1, off);
    s2 += __shfl_xor(s2, off);
    s3 += __shfl_xor(s3, off);
  }
  if (lane == 0) {
    float m = fmaxf(fmaxf(s0, s1), fmaxf(s2, s3));
    float e0 = __expf(s0 - m), e1 = __expf(s1 - m), e2 = __expf(s2 - m), e3 = __expf(s3 - m);
    float inv = 1.0f / (e0 + e1 + e2 + e3);
    float4 g; g.x = e0 * inv; g.y = e1 * inv; g.z = e2 * inv; g.w = e3 * inv;
    *(float4*)(gates + n * 4) = g;
  }
}

// ---------- kernel 2: build W1eff^T bf16 ----------
__global__ __launch_bounds__(256) void build_w1(
    const float* __restrict__ c1, const float* __restrict__ c2,
    unsigned short* __restrict__ w1t) {
  const int kf = blockIdx.x;
  const int k = kf >> 12, f = kf & 4095;
  const int x = f >> 6, y = f & 63;
  __shared__ float s1[32 * 16];
  __shared__ float s2[16 * 32];
  const int t = threadIdx.x;
  for (int i = t; i < 512; i += 256) {
    int a = i >> 4, r = i & 15;
    s1[i] = c1[(((size_t)(k * 32 + a)) * 64 + x) * 16 + r];
  }
  for (int i = t; i < 512; i += 256) {
    int r = i >> 5, b = i & 31;
    s2[i] = c2[(((size_t)(k * 16 + r)) * 32 + b) * 64 + y];
  }
  __syncthreads();
  unsigned short* wrow = w1t + ((size_t)k * DF + f) * DM;
#pragma unroll
  for (int j = 0; j < 4; ++j) {
    int d = t + j * 256;
    int a = d >> 5, b = d & 31;
    float s = 0.f;
#pragma unroll
    for (int r = 0; r < 16; ++r) s += s1[a * 16 + r] * s2[r * 32 + b];
    wrow[d] = f2bf(s);
  }
}

// ---------- kernel 3: build W2eff^T bf16 ----------
__global__ __launch_bounds__(256) void build_w2(
    const float* __restrict__ c1, const float* __restrict__ c2,
    unsigned short* __restrict__ w2t) {
  const int kd = blockIdx.x;
  const int k = kd >> 10, d = kd & 1023;
  const int x = d >> 5, y = d & 31;
  __shared__ float s1[64 * 16];
  __shared__ float s2[16 * 64];
  const int t = threadIdx.x;
  for (int i = t; i < 1024; i += 256) {
    int a = i >> 4, r = i & 15;
    s1[i] = c1[(((size_t)(k * 64 + a)) * 32 + x) * 16 + r];
  }
  for (int i = t; i < 1024; i += 256) {
    int r = i >> 6, b = i & 63;
    s2[i] = c2[(((size_t)(k * 16 + r)) * 64 + b) * 32 + y];
  }
  __syncthreads();
  unsigned short* wrow = w2t + ((size_t)k * DM + d) * DF;
#pragma unroll
  for (int j = 0; j < 16; ++j) {
    int f = t + j * 256;
    int a = f >> 6, b = f & 63;
    float s = 0.f;
#pragma unroll
    for (int r = 0; r < 16; ++r) s += s1[a * 16 + r] * s2[r * 64 + b];
    wrow[f] = f2bf(s);
  }
}

// ---------- kernel 4: GEMM1  hg[k][n][f] = bf16(gelu(x@W1[k]) * gate) ----------
// 128x128 tile, BK=64, XOR-swizzled LDS (chunk ^= row&7) for conflict-free b128 reads.
__global__ __launch_bounds__(256) void gemm1(
    const unsigned short* __restrict__ xb, const unsigned short* __restrict__ w1t,
    const float* __restrict__ gates, unsigned short* __restrict__ hg) {
  __shared__ __align__(16) unsigned short As[128 * 64];
  __shared__ __align__(16) unsigned short Bs[128 * 64];
  const int t = threadIdx.x, lane = t & 63, wv = t >> 6;
  const int m0 = blockIdx.x * 128, n0 = blockIdx.y * 128, kp = blockIdx.z;
  const unsigned short* B = w1t + (size_t)kp * DF * DM;
  f32x4 acc[4][4] = {};
  const int srow = t >> 3;
  const int schunk = ((t & 7) ^ (srow & 7)) * 8;  // swizzled source chunk (elements)
  const int wrow = (wv >> 1) * 64, wcol = (wv & 1) * 64;
  const int fr = lane & 15, quad = lane >> 4;
  const int sw = fr & 7;  // row&7 of every fragment row this lane reads
  char* AsB = (char*)As;
  char* BsB = (char*)Bs;
  for (int k0 = 0; k0 < DM; k0 += 64) {
#pragma unroll
    for (int i = 0; i < 4; ++i) {
      int row = i * 32 + srow;
      gload_lds16(xb + (size_t)(m0 + row) * DM + k0 + schunk, AsB + i * 4096 + t * 16);
      gload_lds16(B + (size_t)(n0 + row) * DM + k0 + schunk, BsB + i * 4096 + t * 16);
    }
    __syncthreads();
#pragma unroll
    for (int kk = 0; kk < 2; ++kk) {
      const int pc = ((kk * 4 + quad) ^ sw) * 8;  // physical chunk offset (elements)
      short8 a[4], b[4];
#pragma unroll
      for (int mi = 0; mi < 4; ++mi)
        a[mi] = *(const short8*)(As + (wrow + mi * 16 + fr) * 64 + pc);
#pragma unroll
      for (int ni = 0; ni < 4; ++ni)
        b[ni] = *(const short8*)(Bs + (wcol + ni * 16 + fr) * 64 + pc);
#pragma unroll
      for (int mi = 0; mi < 4; ++mi)
#pragma unroll
        for (int ni = 0; ni < 4; ++ni)
          acc[mi][ni] = __builtin_amdgcn_mfma_f32_16x16x32_bf16(a[mi], b[ni], acc[mi][ni], 0, 0, 0);
    }
    __syncthreads();
  }
  unsigned short* H = hg + (size_t)kp * N_TOK * DF;
  const int rq = quad * 4;
#pragma unroll
  for (int mi = 0; mi < 4; ++mi) {
#pragma unroll
    for (int i = 0; i < 4; ++i) {
      int row = m0 + wrow + mi * 16 + rq + i;
      float g = gates[row * 4 + kp];
#pragma unroll
      for (int ni = 0; ni < 4; ++ni) {
        float v = acc[mi][ni][i];
        H[(size_t)row * DF + n0 + wcol + ni * 16 + fr] = f2bf(gelu_tanh(v) * g);
      }
    }
  }
}

// ---------- kernel 5: GEMM2 partials  part[k][n][d] = (1+pw[k,d]) * (hg[k]@W2[k])[n,d]
// 128x128 tile, BK=64, kp split across blockIdx.z, same swizzle. fp32 partials.
__global__ __launch_bounds__(256) void gemm2(
    const unsigned short* __restrict__ hg, const unsigned short* __restrict__ w2t,
    const float* __restrict__ pw, float* __restrict__ part) {
  __shared__ __align__(16) unsigned short As[128 * 64];
  __shared__ __align__(16) unsigned short Bs[128 * 64];
  const int t = threadIdx.x, lane = t & 63, wv = t >> 6;
  const int m0 = blockIdx.x * 128, n0 = blockIdx.y * 128, kp = blockIdx.z;
  const unsigned short* A = hg + (size_t)kp * N_TOK * DF;
  const unsigned short* B = w2t + (size_t)kp * DM * DF;
  f32x4 acc[4][4] = {};
  const int srow = t >> 3;
  const int schunk = ((t & 7) ^ (srow & 7)) * 8;
  const int wrow = (wv >> 1) * 64, wcol = (wv & 1) * 64;
  const int fr = lane & 15, quad = lane >> 4;
  const int sw = fr & 7;
  char* AsB = (char*)As;
  char* BsB = (char*)Bs;
  for (int k0 = 0; k0 < DF; k0 += 64) {
#pragma unroll
    for (int i = 0; i < 4; ++i) {
      int row = i * 32 + srow;
      gload_lds16(A + (size_t)(m0 + row) * DF + k0 + schunk, AsB + i * 4096 + t * 16);
      gload_lds16(B + (size_t)(n0 + row) * DF + k0 + schunk, BsB + i * 4096 + t * 16);
    }
    __syncthreads();
#pragma unroll
    for (int kk = 0; kk < 2; ++kk) {
      const int pc = ((kk * 4 + quad) ^ sw) * 8;
      short8 a[4], b[4];
#pragma unroll
      for (int mi = 0; mi < 4; ++mi)
        a[mi] = *(const short8*)(As + (wrow + mi * 16 + fr) * 64 + pc);
#pragma unroll
      for (int ni = 0; ni < 4; ++ni)
        b[ni] = *(const short8*)(Bs + (wcol + ni * 16 + fr) * 64 + pc);
#pragma unroll
      for (int mi = 0; mi < 4; ++mi)
#pragma unroll
        for (int ni = 0; ni < 4; ++ni)
          acc[mi][ni] = __builtin_amdgcn_mfma_f32_16x16x32_bf16(a[mi], b[ni], acc[mi][ni], 0, 0, 0);
    }
    __syncthreads();
  }
  float* P = part + (size_t)kp * N_TOK * DM;
  const int rq = quad * 4;
#pragma unroll
  for (int ni = 0; ni < 4; ++ni) {
    int col = n0 + wcol + ni * 16 + fr;
    float s = 1.0f + pw[kp * DM + col];
#pragma unroll
    for (int mi = 0; mi < 4; ++mi)
#pragma unroll
      for (int i = 0; i < 4; ++i) {
        int row = m0 + wrow + mi * 16 + rq + i;
        P[(size_t)row * DM + col] = s * acc[mi][ni][i];
      }
  }
}

// ---------- kernel 6: reduce partials over k ----------
__global__ __launch_bounds__(256) void reduce_k(
    const float* __restrict__ part, float* __restrict__ out) {
  const size_t i = ((size_t)blockIdx.x * 256 + threadIdx.x) * 4;
  const size_t S = (size_t)N_TOK * DM;
  float4 a = *(const float4*)(part + i);
  float4 b = *(const float4*)(part + S + i);
  float4 c = *(const float4*)(part + 2 * S + i);
  float4 d = *(const float4*)(part + 3 * S + i);
  float4 r;
  r.x = a.x + b.x + c.x + d.x;
  r.y = a.y + b.y + c.y + d.y;
  r.z = a.z + b.z + c.z + d.z;
  r.w = a.w + b.w + c.w + d.w;
  *(float4*)(out + i) = r;
}

// ---------- launcher ----------
extern "C" void kernel_launch(void* const* d_in, const int* in_sizes, int n_in,
                              void* d_out, int out_size, void* d_ws, size_t ws_size,
                              hipStream_t stream) {
  const float* tokens = (const float*)d_in[0];
  const float* f1c1   = (const float*)d_in[1];
  const float* f1c2   = (const float*)d_in[2];
  const float* f2c1   = (const float*)d_in[3];
  const float* f2c2   = (const float*)d_in[4];
  const float* pb     = (const float*)d_in[5];
  const float* pw     = (const float*)d_in[6];
  float* out = (float*)d_out;

  char* ws = (char*)d_ws;
  unsigned short* xb  = (unsigned short*)(ws);                  //   4 MB
  unsigned short* w1t = (unsigned short*)(ws + (4ull  << 20));  //  32 MB (dead after gemm1)
  float*          part = (float*)(ws + (4ull << 20));           //  32 MB (reuses w1t)
  unsigned short* w2t = (unsigned short*)(ws + (36ull << 20));  //  32 MB
  unsigned short* hg  = (unsigned short*)(ws + (68ull << 20));  //  64 MB
  float*          gates = (float*)(ws + (132ull << 20));        //  32 KB

  hipLaunchKernelGGL(prep_kernel, dim3(512), dim3(256), 0, stream, tokens, pb, gates, xb);
  hipLaunchKernelGGL(build_w1, dim3(KP * DF), dim3(256), 0, stream, f1c1, f1c2, w1t);
  hipLaunchKernelGGL(build_w2, dim3(KP * DM), dim3(256), 0, stream, f2c1, f2c2, w2t);
  hipLaunchKernelGGL(gemm1, dim3(16, 32, KP), dim3(256), 0, stream, xb, w1t, gates, hg);
  hipLaunchKernelGGL(gemm2, dim3(16, 8, KP), dim3(256), 0, stream, hg, w2t, pw, part);
  hipLaunchKernelGGL(reduce_k, dim3(2048), dim3(256), 0, stream, part, out);
}